// Round 5
// baseline (2495.663 us; speedup 1.0000x reference)
//
#include <hip/hip_runtime.h>

typedef unsigned short u16;
typedef unsigned int   u32;

#define NB  16
#define NC  256
#define NH  80
#define NW  80
#define NHW 6400

__device__ __forceinline__ float b2f(u16 u) {
  union { u32 i; float f; } c; c.i = ((u32)u) << 16; return c.f;
}
__device__ __forceinline__ u16 f2b(float f) {
  union { float f; u32 i; } c; c.f = f;
  return (u16)((c.i + 0x7FFFu + ((c.i >> 16) & 1u)) >> 16);
}
__device__ __forceinline__ void unpack8(uint4 v, float* f) {
  f[0] = b2f((u16)(v.x & 0xFFFFu)); f[1] = b2f((u16)(v.x >> 16));
  f[2] = b2f((u16)(v.y & 0xFFFFu)); f[3] = b2f((u16)(v.y >> 16));
  f[4] = b2f((u16)(v.z & 0xFFFFu)); f[5] = b2f((u16)(v.z >> 16));
  f[6] = b2f((u16)(v.w & 0xFFFFu)); f[7] = b2f((u16)(v.w >> 16));
}
// dtype-dispatched input load (flag=1: f32, flag=0: bf16)
__device__ __forceinline__ float ldx(const void* p, size_t i, int f32f) {
  return f32f ? ((const float*)p)[i] : b2f(((const u16*)p)[i]);
}

// ---- K0a: detect input dtype. f32 data read as u16 halves shows bf16-NaN
// (exp==0xFF) patterns in mantissa-low words (~1/256 of them); genuine bf16
// activation data never does. flag: 1 = f32 inputs, 0 = bf16 inputs. ----
__global__ __launch_bounds__(256) void probe_dtype(const u16* __restrict__ x,
                                                   int* __restrict__ flag)
{
  __shared__ int cnt[256];
  int c = 0;
  for (int i = threadIdx.x; i < 262144; i += 256) {
    u16 u = x[i];
    if (((u >> 7) & 0xFF) == 0xFF) c++;
  }
  cnt[threadIdx.x] = c; __syncthreads();
  for (int s = 128; s > 0; s >>= 1) {
    if (threadIdx.x < s) cnt[threadIdx.x] += cnt[threadIdx.x + s];
    __syncthreads();
  }
  if (threadIdx.x == 0) *flag = (cnt[0] > 16) ? 1 : 0;
}

// ---- K0b: convert all 18 weight/bias arrays into one f32 table ----
struct CvtArgs { const void* src[18]; int cum[19]; };

__global__ __launch_bounds__(256) void cvt_weights(CvtArgs a, float* __restrict__ dst,
                                                   const int* __restrict__ flag)
{
  int f = *flag;
  int i = blockIdx.x * 256 + threadIdx.x;     // < 153600
  int s = 0;
  while (i >= a.cum[s + 1]) s++;
  int j = i - a.cum[s];
  float v = f ? ((const float*)a.src[s])[j] : b2f(((const u16*)a.src[s])[j]);
  if (!(v == v) || fabsf(v) > 1e30f) v = 0.f;  // scrub
  dst[i] = v;
}

// ---- K1: per-pixel LN stats (mean, rstd) over C, straight from x ----
__global__ __launch_bounds__(256) void ln_stats(const void* __restrict__ xsrc,
    size_t xoff, const int* __restrict__ flag, float2* __restrict__ stats)
{
  int f = *flag;
  int p = blockIdx.x * 256 + threadIdx.x;      // [0, Nb*NHW)
  int bl = p / NHW, hw = p % NHW;
  size_t base = xoff + (size_t)bl * NC * NHW + hw;
  float s1 = 0.f, s2 = 0.f;
  for (int c = 0; c < NC; c++) {
    float v = ldx(xsrc, base + (size_t)c * NHW, f);
    s1 += v; s2 += v * v;
  }
  float mean = s1 * (1.f / 256.f);
  float var  = s2 * (1.f / 256.f) - mean * mean;
  stats[p] = make_float2(mean, rsqrtf(var + 1e-5f));
}

// ---- K2: fused LN + depthwise conv (combined 21-tap), horiz or vert ----
__global__ __launch_bounds__(256) void dw_fused(const void* __restrict__ xsrc,
    size_t xoff, const int* __restrict__ flag,
    const float2* __restrict__ stats,
    const float* __restrict__ g, const float* __restrict__ bt,
    const float* __restrict__ w7,  const float* __restrict__ b7,
    const float* __restrict__ w11, const float* __restrict__ b11,
    const float* __restrict__ w21, const float* __restrict__ b21,
    u16* __restrict__ dst, int vertical)
{
  __shared__ float cw[21];
  __shared__ float cb, cg, cbt;
  int f = *flag;
  int base = blockIdx.x * 256;                 // < Nb*NC*NHW
  int c  = (base / NHW) % NC;
  int bl = base / (NC * NHW);
  int t = threadIdx.x;
  if (t < 21) {
    float v = w21[c * 21 + t];
    if (t >= 5 && t <= 15) v += w11[c * 11 + t - 5];
    if (t >= 7 && t <= 13) v += w7[c * 7 + t - 7];
    cw[t] = v;
  } else if (t == 21) { cb = b7[c] + b11[c] + b21[c]; }
  else if (t == 22) { cg = g[c]; }
  else if (t == 23) { cbt = bt[c]; }
  __syncthreads();
  int hw = base % NHW + t;                     // base%NHW is mult of 256
  int h = hw / NW, w = hw % NW;
  size_t xrow = xoff + ((size_t)bl * NC + c) * NHW;
  const float2* st = stats + (size_t)bl * NHW;
  float a = cb;
  if (!vertical) {
    #pragma unroll
    for (int d = -10; d <= 10; d++) {
      int wp = w + d;
      if (wp >= 0 && wp < NW) {
        int q = h * NW + wp;
        float2 s = st[q];
        a += cw[d + 10] * ((ldx(xsrc, xrow + q, f) - s.x) * s.y * cg + cbt);
      }
    }
  } else {
    #pragma unroll
    for (int d = -10; d <= 10; d++) {
      int hp = h + d;
      if (hp >= 0 && hp < NH) {
        int q = hp * NW + w;
        float2 s = st[q];
        a += cw[d + 10] * ((ldx(xsrc, xrow + q, f) - s.x) * s.y * cg + cbt);
      }
    }
  }
  dst[(size_t)base + t] = f2b(a);
}

// ---- K3: IN-PLACE pointwise conv on a bf16 ws buffer. Block owns a
// self-contained strip [256 ch x 64 px]: io[bl,o,p] <- bias[o] + sum_k W[o,k]*io[bl,k,p]. ----
__global__ __launch_bounds__(256) void pw_inplace(const float* __restrict__ Wt,
    u16* io, const float* __restrict__ bias)
{
  __shared__ u16 Is[256][64];     // input strip [k][p]   (32 KB)
  __shared__ float Ws[8][256];    // W panel  [kk][o]     (8 KB)
  int bl = blockIdx.y;
  int p0 = blockIdx.x * 64;
  int t = threadIdx.x;
  {
    const u16* src = io + ((size_t)bl * NC + t) * NHW + p0;
    uint4* dstv = (uint4*)&Is[t][0];
    #pragma unroll
    for (int j = 0; j < 8; j++) dstv[j] = *(const uint4*)(src + j * 8);
  }
  __syncthreads();
  int to = t >> 3, tp = t & 7;    // o-frag [0,32), p-frag [0,8)
  float acc[8][8] = {};
  for (int k0 = 0; k0 < 256; k0 += 8) {
    float4 wa = *(const float4*)(Wt + (size_t)t * 256 + k0);
    float4 wb = *(const float4*)(Wt + (size_t)t * 256 + k0 + 4);
    __syncthreads();              // prior iter readers done
    Ws[0][t] = wa.x; Ws[1][t] = wa.y; Ws[2][t] = wa.z; Ws[3][t] = wa.w;
    Ws[4][t] = wb.x; Ws[5][t] = wb.y; Ws[6][t] = wb.z; Ws[7][t] = wb.w;
    __syncthreads();
    #pragma unroll
    for (int kk = 0; kk < 8; kk++) {
      float4 a0 = *(float4*)&Ws[kk][to * 8];
      float4 a1 = *(float4*)&Ws[kk][to * 8 + 4];
      uint4 bv = *(uint4*)&Is[k0 + kk][tp * 8];
      float bb[8]; unpack8(bv, bb);
      float a[8] = {a0.x, a0.y, a0.z, a0.w, a1.x, a1.y, a1.z, a1.w};
      #pragma unroll
      for (int r = 0; r < 8; r++)
        #pragma unroll
        for (int s = 0; s < 8; s++)
          acc[r][s] += a[r] * bb[s];
    }
  }
  #pragma unroll
  for (int r = 0; r < 8; r++) {
    int o = to * 8 + r;
    float bv = bias[o];
    size_t idx = ((size_t)bl * NC + o) * NHW + p0 + tp * 8;
    ushort4 v0, v1;
    v0.x = f2b(acc[r][0] + bv); v0.y = f2b(acc[r][1] + bv);
    v0.z = f2b(acc[r][2] + bv); v0.w = f2b(acc[r][3] + bv);
    v1.x = f2b(acc[r][4] + bv); v1.y = f2b(acc[r][5] + bv);
    v1.z = f2b(acc[r][6] + bv); v1.w = f2b(acc[r][7] + bv);
    *(ushort4*)(io + idx)     = v0;
    *(ushort4*)(io + idx + 4) = v1;
  }
}

// ---- K8: final pointwise: Out = 2*bias + W*In + x, written in the OUTPUT dtype
// (f32 if flag else bf16). In = bf16 attention result; x read straight from d_in. ----
__global__ __launch_bounds__(256) void pw_final(const float* __restrict__ Wt,
    const u16* __restrict__ In, void* __restrict__ OutBase, size_t out_off,
    const float* __restrict__ bias,
    const void* __restrict__ xsrc, size_t xoff, const int* __restrict__ flag)
{
  __shared__ u16 Is[256][64];
  __shared__ float Ws[8][256];
  int f = *flag;
  int bl = blockIdx.y;
  int p0 = blockIdx.x * 64;
  int t = threadIdx.x;
  {
    const u16* src = In + ((size_t)bl * NC + t) * NHW + p0;
    uint4* dstv = (uint4*)&Is[t][0];
    #pragma unroll
    for (int j = 0; j < 8; j++) dstv[j] = *(const uint4*)(src + j * 8);
  }
  __syncthreads();
  int to = t >> 3, tp = t & 7;
  float acc[8][8] = {};
  for (int k0 = 0; k0 < 256; k0 += 8) {
    float4 wa = *(const float4*)(Wt + (size_t)t * 256 + k0);
    float4 wb = *(const float4*)(Wt + (size_t)t * 256 + k0 + 4);
    __syncthreads();
    Ws[0][t] = wa.x; Ws[1][t] = wa.y; Ws[2][t] = wa.z; Ws[3][t] = wa.w;
    Ws[4][t] = wb.x; Ws[5][t] = wb.y; Ws[6][t] = wb.z; Ws[7][t] = wb.w;
    __syncthreads();
    #pragma unroll
    for (int kk = 0; kk < 8; kk++) {
      float4 a0 = *(float4*)&Ws[kk][to * 8];
      float4 a1 = *(float4*)&Ws[kk][to * 8 + 4];
      uint4 bv = *(uint4*)&Is[k0 + kk][tp * 8];
      float bb[8]; unpack8(bv, bb);
      float a[8] = {a0.x, a0.y, a0.z, a0.w, a1.x, a1.y, a1.z, a1.w};
      #pragma unroll
      for (int r = 0; r < 8; r++)
        #pragma unroll
        for (int s = 0; s < 8; s++)
          acc[r][s] += a[r] * bb[s];
    }
  }
  #pragma unroll
  for (int r = 0; r < 8; r++) {
    int o = to * 8 + r;
    float bv = 2.f * bias[o];
    size_t idx = ((size_t)bl * NC + o) * NHW + p0 + tp * 8;
    #pragma unroll
    for (int s = 0; s < 8; s++) {
      float v = acc[r][s] + bv + ldx(xsrc, xoff + idx + s, f);
      if (f) ((float*)OutBase)[out_off + idx + s] = v;
      else   ((u16*)OutBase)[out_off + idx + s]   = f2b(v);
    }
  }
}

// ---- K4: per-(bl,c) row/col sum of squares ----
__global__ __launch_bounds__(256) void rowcol_sumsq(const u16* __restrict__ fx, const u16* __restrict__ fy,
    float* __restrict__ rs_fx, float* __restrict__ rs_fy,
    float* __restrict__ cs_fx, float* __restrict__ cs_fy)
{
  __shared__ float tile[80][81];
  int bc = blockIdx.x; int ten = blockIdx.y;
  const u16* src = (ten ? fy : fx) + (size_t)bc * NHW;
  int t = threadIdx.x;
  for (int i = t; i < NHW; i += 256) {
    float v = b2f(src[i]);
    tile[i / 80][i % 80] = v * v;
  }
  __syncthreads();
  if (t < 80) {
    float s = 0.f;
    #pragma unroll
    for (int k = 0; k < 80; k++) s += tile[t][k];
    (ten ? rs_fy : rs_fx)[bc * 80 + t] = s;
  } else if (t < 160) {
    int w = t - 80; float s = 0.f;
    #pragma unroll
    for (int h = 0; h < 80; h++) s += tile[h][w];
    (ten ? cs_fy : cs_fx)[bc * 80 + w] = s;
  }
}

// ---- K5: combine over ci -> inverse norms.
// invn: [0]=H_fy(q) [Nb*640]=H_fx(k) [2*Nb*640]=W_fx(q) [3*Nb*640]=W_fy(k) ----
__global__ __launch_bounds__(256) void norm_combine(const float* __restrict__ rs_fx,
    const float* __restrict__ rs_fy, const float* __restrict__ cs_fx,
    const float* __restrict__ cs_fy, float* __restrict__ invn, int Nb)
{
  int t = blockIdx.x * 256 + threadIdx.x;   // 4*Nb*640 total
  int blk = Nb * 640;
  int side = t / blk, r = t % blk;
  int b = r / 640, rem = r % 640, hd = rem / 80, row = rem % 80;
  const float* src = (side == 0) ? rs_fy : (side == 1) ? rs_fx : (side == 2) ? cs_fx : cs_fy;
  size_t base = (size_t)(b * 256 + hd * 32) * 80 + row;
  float s = 0.f;
  #pragma unroll
  for (int ci = 0; ci < 32; ci++) s += src[base + ci * 80];
  invn[t] = 1.f / fmaxf(sqrtf(s), 1e-12f);
}

// ---- K6: Gram (sum over 32 ci) + cosine scale + softmax -> Sbuf ----
__global__ __launch_bounds__(256) void gram_softmax(const u16* __restrict__ fx, const u16* __restrict__ fy,
    const float* __restrict__ invn, u16* __restrict__ Sbuf, int Nb)
{
  __shared__ float At[80][81];
  __shared__ float Bt[80][81];
  int hd = blockIdx.x, b = blockIdx.y, axis = blockIdx.z;
  const u16* A  = axis ? fx : fy;   // q-side
  const u16* Bm = axis ? fy : fx;   // k-side
  size_t sl0 = (size_t)(b * 256 + hd * 32) * NHW;
  int t = threadIdx.x, tx = t & 15, ty = t >> 4;
  float acc[5][5] = {};
  for (int ci = 0; ci < 32; ci++) {
    const u16* pa = A  + sl0 + (size_t)ci * NHW;
    const u16* pb = Bm + sl0 + (size_t)ci * NHW;
    for (int i = t; i < NHW; i += 256) {
      int h = i / 80, w = i % 80;
      float va = b2f(pa[i]), vb = b2f(pb[i]);
      if (axis == 0) { At[h][w] = va; Bt[h][w] = vb; }
      else           { At[w][h] = va; Bt[w][h] = vb; }
    }
    __syncthreads();
    for (int k = 0; k < 80; k++) {
      float a[5], bb[5];
      #pragma unroll
      for (int r = 0; r < 5; r++) a[r] = At[ty + 16 * r][k];
      #pragma unroll
      for (int s = 0; s < 5; s++) bb[s] = Bt[tx + 16 * s][k];
      #pragma unroll
      for (int r = 0; r < 5; r++)
        #pragma unroll
        for (int s = 0; s < 5; s++)
          acc[r][s] += a[r] * bb[s];
    }
    __syncthreads();
  }
  int blk = Nb * 640;
  int rowbase = (b * 8 + hd) * 80;
  const float* invq = invn + (axis ? 2 * blk : 0)   + rowbase;
  const float* invk = invn + (axis ? 3 * blk : blk) + rowbase;
  #pragma unroll
  for (int r = 0; r < 5; r++)
    #pragma unroll
    for (int s = 0; s < 5; s++) {
      float gv = acc[r][s] * invq[ty + 16 * r] * invk[tx + 16 * s];
      At[ty + 16 * r][tx + 16 * s] = fminf(fmaxf(gv, -8.f), 8.f);  // |cos|<=1; NaN->-8
    }
  __syncthreads();
  u16* Sg = Sbuf + ((size_t)(axis * Nb * 8 + b * 8 + hd)) * NHW;
  if (t < 80) {
    float m = -1e30f;
    for (int j = 0; j < 80; j++) m = fmaxf(m, At[t][j]);
    float s = 0.f;
    for (int j = 0; j < 80; j++) s += __expf(At[t][j] - m);
    float inv = 1.f / s;
    for (int j = 0; j < 80; j++) Sg[t * 80 + j] = f2b(__expf(At[t][j] - m) * inv);
  }
}

// ---- K7: fused H+W attention apply, IN PLACE over fx slice ----
__global__ __launch_bounds__(256) void apply_hw(const u16* __restrict__ fy_g,
    const u16* __restrict__ Sbuf, const float* __restrict__ invn, u16* fx_io, int Nb)
{
  __shared__ float SH[80][81];
  __shared__ float SW[80][81];
  __shared__ float FX[80][81];
  __shared__ float FY[80][81];
  int ci = blockIdx.x, hd = blockIdx.y, b = blockIdx.z;
  size_t off = (size_t)(b * 256 + hd * 32 + ci) * NHW;
  const u16* SgH = Sbuf + (size_t)(b * 8 + hd) * NHW;
  const u16* SgW = Sbuf + ((size_t)(Nb * 8) + b * 8 + hd) * NHW;
  int t = threadIdx.x, tx = t & 15, ty = t >> 4;
  for (int i = t; i < NHW; i += 256) {
    int h = i / 80, w = i % 80;
    SH[h][w] = b2f(SgH[i]);
    SW[h][w] = b2f(SgW[i]);
    FX[h][w] = b2f(fx_io[off + i]);
    FY[h][w] = b2f(fy_g[off + i]);
  }
  __syncthreads();
  float accH[5][5] = {}, accW[5][5] = {};
  for (int k = 0; k < 80; k++) {
    float a[5], bv[5], c[5], d[5];
    #pragma unroll
    for (int r = 0; r < 5; r++) a[r] = SH[ty + 16 * r][k];   // S_H[h][k]
    #pragma unroll
    for (int s = 0; s < 5; s++) bv[s] = FX[k][tx + 16 * s];  // fx[k][w]
    #pragma unroll
    for (int r = 0; r < 5; r++) c[r] = FY[ty + 16 * r][k];   // fy[h][k]
    #pragma unroll
    for (int s = 0; s < 5; s++) d[s] = SW[tx + 16 * s][k];   // S_W[w][k]
    #pragma unroll
    for (int r = 0; r < 5; r++)
      #pragma unroll
      for (int s = 0; s < 5; s++) {
        accH[r][s] += a[r] * bv[s];
        accW[r][s] += c[r] * d[s];
      }
  }
  const float* invqH = invn + (b * 8 + hd) * 80;                 // H_fy(q)
  const float* invqW = invn + 2 * Nb * 640 + (b * 8 + hd) * 80;  // W_fx(q)
  #pragma unroll
  for (int r = 0; r < 5; r++)
    #pragma unroll
    for (int s = 0; s < 5; s++) {
      int h = ty + 16 * r, w = tx + 16 * s;
      float v = accH[r][s] + accW[r][s] + FY[h][w] * invqH[h] + FX[h][w] * invqW[w];
      fx_io[off + h * 80 + w] = f2b(v);
    }
}

extern "C" void kernel_launch(void* const* d_in, const int* in_sizes, int n_in,
                              void* d_out, int out_size, void* d_ws, size_t ws_size,
                              hipStream_t stream) {
  // Weight conversion table: d_in[1..18] in setup_inputs order.
  const int wsz[18] = {256, 256, 65536, 256, 65536, 256,
                       1792, 256, 2816, 256, 5376, 256,
                       1792, 256, 2816, 256, 5376, 256};
  CvtArgs ca;
  int cum = 0;
  for (int i = 0; i < 18; i++) { ca.src[i] = d_in[i + 1]; ca.cum[i] = cum; cum += wsz[i]; }
  ca.cum[18] = cum;   // 153600

  // ws layout: flag(16) | wbuf(614400) | per-chunk (Nb * 7,147,520).
  int Nb = 1;
  for (int cand = 16; cand >= 1; cand >>= 1) {
    size_t need = (size_t)cand * 7147520 + 614416;
    if (need <= ws_size) { Nb = cand; break; }
  }
  char* p = (char*)d_ws;
  int*    flag  = (int*)p;    p += 16;
  float*  wbuf  = (float*)p;  p += 614400;
  u16*    fxbuf = (u16*)p;    p += (size_t)Nb * 3276800;
  u16*    fybuf = (u16*)p;    p += (size_t)Nb * 3276800;
  float2* stats = (float2*)p; p += (size_t)Nb * 51200;
  float*  rs_fx = (float*)p;  p += (size_t)Nb * 81920;
  float*  rs_fy = (float*)p;  p += (size_t)Nb * 81920;
  float*  cs_fx = (float*)p;  p += (size_t)Nb * 81920;
  float*  cs_fy = (float*)p;  p += (size_t)Nb * 81920;
  float*  invn  = (float*)p;  p += (size_t)Nb * 10240;
  u16*    Sbuf  = (u16*)p;

  // f32 weight views
  float* ln_g = wbuf + ca.cum[0];  float* ln_b = wbuf + ca.cum[1];
  float* w_in = wbuf + ca.cum[2];  float* b_in = wbuf + ca.cum[3];
  float* w_out= wbuf + ca.cum[4];  float* b_out= wbuf + ca.cum[5];
  float* wx7  = wbuf + ca.cum[6];  float* bx7  = wbuf + ca.cum[7];
  float* wx11 = wbuf + ca.cum[8];  float* bx11 = wbuf + ca.cum[9];
  float* wx21 = wbuf + ca.cum[10]; float* bx21 = wbuf + ca.cum[11];
  float* wy7  = wbuf + ca.cum[12]; float* by7  = wbuf + ca.cum[13];
  float* wy11 = wbuf + ca.cum[14]; float* by11 = wbuf + ca.cum[15];
  float* wy21 = wbuf + ca.cum[16]; float* by21 = wbuf + ca.cum[17];

  probe_dtype<<<dim3(1), dim3(256), 0, stream>>>((const u16*)d_in[0], flag);
  cvt_weights<<<dim3(600), dim3(256), 0, stream>>>(ca, wbuf, flag);

  for (int b0 = 0; b0 < NB; b0 += Nb) {
    size_t xoff = (size_t)b0 * NC * NHW;   // element offset of chunk in x / out

    ln_stats<<<dim3(Nb * 25), dim3(256), 0, stream>>>(d_in[0], xoff, flag, stats);
    dw_fused<<<dim3(Nb * 6400), dim3(256), 0, stream>>>(d_in[0], xoff, flag, stats,
        ln_g, ln_b, wx7, bx7, wx11, bx11, wx21, bx21, fxbuf, 0);
    pw_inplace<<<dim3(100, Nb), dim3(256), 0, stream>>>(w_in, fxbuf, b_in);
    dw_fused<<<dim3(Nb * 6400), dim3(256), 0, stream>>>(d_in[0], xoff, flag, stats,
        ln_g, ln_b, wy7, by7, wy11, by11, wy21, by21, fybuf, 1);
    pw_inplace<<<dim3(100, Nb), dim3(256), 0, stream>>>(w_in, fybuf, b_in);
    rowcol_sumsq<<<dim3(Nb * 256, 2), dim3(256), 0, stream>>>(fxbuf, fybuf, rs_fx, rs_fy, cs_fx, cs_fy);
    norm_combine<<<dim3(10 * Nb), dim3(256), 0, stream>>>(rs_fx, rs_fy, cs_fx, cs_fy, invn, Nb);
    gram_softmax<<<dim3(8, Nb, 2), dim3(256), 0, stream>>>(fxbuf, fybuf, invn, Sbuf, Nb);
    apply_hw<<<dim3(32, 8, Nb), dim3(256), 0, stream>>>(fybuf, Sbuf, invn, fxbuf, Nb);
    pw_final<<<dim3(100, Nb), dim3(256), 0, stream>>>(w_out, fxbuf, d_out, xoff, b_out,
                                                      d_in[0], xoff, flag);
  }
  (void)in_sizes; (void)n_in; (void)out_size;
}

// Round 6
// 1888.774 us; speedup vs baseline: 1.3213x; 1.3213x over previous
//
#include <hip/hip_runtime.h>

typedef unsigned short u16;
typedef unsigned int   u32;

#define NB  16
#define NC  256
#define NH  80
#define NW  80
#define NHW 6400

__device__ __forceinline__ float b2f(u16 u) {
  union { u32 i; float f; } c; c.i = ((u32)u) << 16; return c.f;
}
__device__ __forceinline__ u16 f2b(float f) {
  union { float f; u32 i; } c; c.f = f;
  return (u16)((c.i + 0x7FFFu + ((c.i >> 16) & 1u)) >> 16);
}
__device__ __forceinline__ void unpack8(uint4 v, float* f) {
  f[0] = b2f((u16)(v.x & 0xFFFFu)); f[1] = b2f((u16)(v.x >> 16));
  f[2] = b2f((u16)(v.y & 0xFFFFu)); f[3] = b2f((u16)(v.y >> 16));
  f[4] = b2f((u16)(v.z & 0xFFFFu)); f[5] = b2f((u16)(v.z >> 16));
  f[6] = b2f((u16)(v.w & 0xFFFFu)); f[7] = b2f((u16)(v.w >> 16));
}
// dtype-dispatched input load (flag=1: f32, flag=0: bf16)
__device__ __forceinline__ float ldx(const void* p, size_t i, int f32f) {
  return f32f ? ((const float*)p)[i] : b2f(((const u16*)p)[i]);
}

// ---- K0a: detect input dtype (1 = f32, 0 = bf16); see round-4 notes ----
__global__ __launch_bounds__(256) void probe_dtype(const u16* __restrict__ x,
                                                   int* __restrict__ flag)
{
  __shared__ int cnt[256];
  int c = 0;
  for (int i = threadIdx.x; i < 262144; i += 256) {
    u16 u = x[i];
    if (((u >> 7) & 0xFF) == 0xFF) c++;
  }
  cnt[threadIdx.x] = c; __syncthreads();
  for (int s = 128; s > 0; s >>= 1) {
    if (threadIdx.x < s) cnt[threadIdx.x] += cnt[threadIdx.x + s];
    __syncthreads();
  }
  if (threadIdx.x == 0) *flag = (cnt[0] > 16) ? 1 : 0;
}

// ---- K0b: convert all 18 weight/bias arrays into one f32 table ----
struct CvtArgs { const void* src[18]; int cum[19]; };

__global__ __launch_bounds__(256) void cvt_weights(CvtArgs a, float* __restrict__ dst,
                                                   const int* __restrict__ flag)
{
  int f = *flag;
  int i = blockIdx.x * 256 + threadIdx.x;     // < 153600
  int s = 0;
  while (i >= a.cum[s + 1]) s++;
  int j = i - a.cum[s];
  float v = f ? ((const float*)a.src[s])[j] : b2f(((const u16*)a.src[s])[j]);
  if (!(v == v) || fabsf(v) > 1e30f) v = 0.f;  // scrub
  dst[i] = v;
}

// ---- K1: per-pixel LN stats (mean, rstd) over C, straight from x ----
__global__ __launch_bounds__(256) void ln_stats(const void* __restrict__ xsrc,
    size_t xoff, const int* __restrict__ flag, float2* __restrict__ stats)
{
  int f = *flag;
  int p = blockIdx.x * 256 + threadIdx.x;      // [0, Nb*NHW)
  int bl = p / NHW, hw = p % NHW;
  size_t base = xoff + (size_t)bl * NC * NHW + hw;
  float s1 = 0.f, s2 = 0.f;
  for (int c = 0; c < NC; c++) {
    float v = ldx(xsrc, base + (size_t)c * NHW, f);
    s1 += v; s2 += v * v;
  }
  float mean = s1 * (1.f / 256.f);
  float var  = s2 * (1.f / 256.f) - mean * mean;
  stats[p] = make_float2(mean, rsqrtf(var + 1e-5f));
}

// ---- K2: fused LN + BOTH depthwise convs from one LDS-staged plane.
// One block per (bl,c) 80x80 plane: x read once, LN applied once, 21-tap
// horizontal and vertical stencils both served from LDS. ----
__global__ __launch_bounds__(256) void dw_both(const void* __restrict__ xsrc,
    size_t xoff, const int* __restrict__ flag,
    const float2* __restrict__ stats,
    const float* __restrict__ g, const float* __restrict__ bt,
    const float* __restrict__ wx7,  const float* __restrict__ bx7,
    const float* __restrict__ wx11, const float* __restrict__ bx11,
    const float* __restrict__ wx21, const float* __restrict__ bx21,
    const float* __restrict__ wy7,  const float* __restrict__ by7,
    const float* __restrict__ wy11, const float* __restrict__ by11,
    const float* __restrict__ wy21, const float* __restrict__ by21,
    u16* __restrict__ sx, u16* __restrict__ sy)
{
  __shared__ float xn[80][81];          // normalized plane, +1 pad
  __shared__ float cwx[21], cwy[21];
  __shared__ float cbx, cby;
  int f = *flag;
  int bc = blockIdx.x;                  // bl*256 + c  ==  plane index in chunk
  int c  = bc & 255;
  int bl = bc >> 8;
  int t = threadIdx.x;
  if (t < 21) {
    float v = wx21[c * 21 + t];
    if (t >= 5 && t <= 15) v += wx11[c * 11 + t - 5];
    if (t >= 7 && t <= 13) v += wx7[c * 7 + t - 7];
    cwx[t] = v;
  } else if (t < 42) {
    int j = t - 21;
    float v = wy21[c * 21 + j];
    if (j >= 5 && j <= 15) v += wy11[c * 11 + j - 5];
    if (j >= 7 && j <= 13) v += wy7[c * 7 + j - 7];
    cwy[j] = v;
  } else if (t == 42) { cbx = bx7[c] + bx11[c] + bx21[c]; }
  else if (t == 43)   { cby = by7[c] + by11[c] + by21[c]; }
  float cg = g[c], cbt = bt[c];         // uniform scalar loads
  size_t xrow = xoff + (size_t)bc * NHW;
  const float2* st = stats + (size_t)bl * NHW;
  for (int i = t; i < NHW; i += 256) {
    float v = ldx(xsrc, xrow + i, f);
    float2 s = st[i];
    xn[i / 80][i % 80] = (v - s.x) * s.y * cg + cbt;
  }
  __syncthreads();
  float bxv = cbx, byv = cby;
  size_t obase = (size_t)bc * NHW;
  for (int k = 0; k < 25; k++) {        // 25*256 = 6400 pixels
    int p = t + 256 * k;
    int h = p / 80, w = p % 80;
    float ax = bxv, ay = byv;
    #pragma unroll
    for (int d = -10; d <= 10; d++) {
      int wp = w + d;
      if (wp >= 0 && wp < NW) ax += cwx[d + 10] * xn[h][wp];
      int hp = h + d;
      if (hp >= 0 && hp < NH) ay += cwy[d + 10] * xn[hp][w];
    }
    sx[obase + p] = f2b(ax);
    sy[obase + p] = f2b(ay);
  }
}

// ---- K3: IN-PLACE pointwise conv on a bf16 ws buffer. Block owns a
// self-contained strip [256 ch x 64 px]: io[bl,o,p] <- bias[o] + sum_k W[o,k]*io[bl,k,p]. ----
__global__ __launch_bounds__(256) void pw_inplace(const float* __restrict__ Wt,
    u16* io, const float* __restrict__ bias)
{
  __shared__ u16 Is[256][64];     // input strip [k][p]   (32 KB)
  __shared__ float Ws[8][256];    // W panel  [kk][o]     (8 KB)
  int bl = blockIdx.y;
  int p0 = blockIdx.x * 64;
  int t = threadIdx.x;
  {
    const u16* src = io + ((size_t)bl * NC + t) * NHW + p0;
    uint4* dstv = (uint4*)&Is[t][0];
    #pragma unroll
    for (int j = 0; j < 8; j++) dstv[j] = *(const uint4*)(src + j * 8);
  }
  __syncthreads();
  int to = t >> 3, tp = t & 7;    // o-frag [0,32), p-frag [0,8)
  float acc[8][8] = {};
  for (int k0 = 0; k0 < 256; k0 += 8) {
    float4 wa = *(const float4*)(Wt + (size_t)t * 256 + k0);
    float4 wb = *(const float4*)(Wt + (size_t)t * 256 + k0 + 4);
    __syncthreads();              // prior iter readers done
    Ws[0][t] = wa.x; Ws[1][t] = wa.y; Ws[2][t] = wa.z; Ws[3][t] = wa.w;
    Ws[4][t] = wb.x; Ws[5][t] = wb.y; Ws[6][t] = wb.z; Ws[7][t] = wb.w;
    __syncthreads();
    #pragma unroll
    for (int kk = 0; kk < 8; kk++) {
      float4 a0 = *(float4*)&Ws[kk][to * 8];
      float4 a1 = *(float4*)&Ws[kk][to * 8 + 4];
      uint4 bv = *(uint4*)&Is[k0 + kk][tp * 8];
      float bb[8]; unpack8(bv, bb);
      float a[8] = {a0.x, a0.y, a0.z, a0.w, a1.x, a1.y, a1.z, a1.w};
      #pragma unroll
      for (int r = 0; r < 8; r++)
        #pragma unroll
        for (int s = 0; s < 8; s++)
          acc[r][s] += a[r] * bb[s];
    }
  }
  #pragma unroll
  for (int r = 0; r < 8; r++) {
    int o = to * 8 + r;
    float bv = bias[o];
    size_t idx = ((size_t)bl * NC + o) * NHW + p0 + tp * 8;
    ushort4 v0, v1;
    v0.x = f2b(acc[r][0] + bv); v0.y = f2b(acc[r][1] + bv);
    v0.z = f2b(acc[r][2] + bv); v0.w = f2b(acc[r][3] + bv);
    v1.x = f2b(acc[r][4] + bv); v1.y = f2b(acc[r][5] + bv);
    v1.z = f2b(acc[r][6] + bv); v1.w = f2b(acc[r][7] + bv);
    *(ushort4*)(io + idx)     = v0;
    *(ushort4*)(io + idx + 4) = v1;
  }
}

// ---- K8: final pointwise: Out = 2*bias + W*In + x, written in the OUTPUT dtype
// (f32 if flag else bf16). In = bf16 attention result; x read straight from d_in. ----
__global__ __launch_bounds__(256) void pw_final(const float* __restrict__ Wt,
    const u16* __restrict__ In, void* __restrict__ OutBase, size_t out_off,
    const float* __restrict__ bias,
    const void* __restrict__ xsrc, size_t xoff, const int* __restrict__ flag)
{
  __shared__ u16 Is[256][64];
  __shared__ float Ws[8][256];
  int f = *flag;
  int bl = blockIdx.y;
  int p0 = blockIdx.x * 64;
  int t = threadIdx.x;
  {
    const u16* src = In + ((size_t)bl * NC + t) * NHW + p0;
    uint4* dstv = (uint4*)&Is[t][0];
    #pragma unroll
    for (int j = 0; j < 8; j++) dstv[j] = *(const uint4*)(src + j * 8);
  }
  __syncthreads();
  int to = t >> 3, tp = t & 7;
  float acc[8][8] = {};
  for (int k0 = 0; k0 < 256; k0 += 8) {
    float4 wa = *(const float4*)(Wt + (size_t)t * 256 + k0);
    float4 wb = *(const float4*)(Wt + (size_t)t * 256 + k0 + 4);
    __syncthreads();
    Ws[0][t] = wa.x; Ws[1][t] = wa.y; Ws[2][t] = wa.z; Ws[3][t] = wa.w;
    Ws[4][t] = wb.x; Ws[5][t] = wb.y; Ws[6][t] = wb.z; Ws[7][t] = wb.w;
    __syncthreads();
    #pragma unroll
    for (int kk = 0; kk < 8; kk++) {
      float4 a0 = *(float4*)&Ws[kk][to * 8];
      float4 a1 = *(float4*)&Ws[kk][to * 8 + 4];
      uint4 bv = *(uint4*)&Is[k0 + kk][tp * 8];
      float bb[8]; unpack8(bv, bb);
      float a[8] = {a0.x, a0.y, a0.z, a0.w, a1.x, a1.y, a1.z, a1.w};
      #pragma unroll
      for (int r = 0; r < 8; r++)
        #pragma unroll
        for (int s = 0; s < 8; s++)
          acc[r][s] += a[r] * bb[s];
    }
  }
  #pragma unroll
  for (int r = 0; r < 8; r++) {
    int o = to * 8 + r;
    float bv = 2.f * bias[o];
    size_t idx = ((size_t)bl * NC + o) * NHW + p0 + tp * 8;
    #pragma unroll
    for (int s = 0; s < 8; s++) {
      float v = acc[r][s] + bv + ldx(xsrc, xoff + idx + s, f);
      if (f) ((float*)OutBase)[out_off + idx + s] = v;
      else   ((u16*)OutBase)[out_off + idx + s]   = f2b(v);
    }
  }
}

// ---- K4: per-(bl,c) row/col sum of squares ----
__global__ __launch_bounds__(256) void rowcol_sumsq(const u16* __restrict__ fx, const u16* __restrict__ fy,
    float* __restrict__ rs_fx, float* __restrict__ rs_fy,
    float* __restrict__ cs_fx, float* __restrict__ cs_fy)
{
  __shared__ float tile[80][81];
  int bc = blockIdx.x; int ten = blockIdx.y;
  const u16* src = (ten ? fy : fx) + (size_t)bc * NHW;
  int t = threadIdx.x;
  for (int i = t; i < NHW; i += 256) {
    float v = b2f(src[i]);
    tile[i / 80][i % 80] = v * v;
  }
  __syncthreads();
  if (t < 80) {
    float s = 0.f;
    #pragma unroll
    for (int k = 0; k < 80; k++) s += tile[t][k];
    (ten ? rs_fy : rs_fx)[bc * 80 + t] = s;
  } else if (t < 160) {
    int w = t - 80; float s = 0.f;
    #pragma unroll
    for (int h = 0; h < 80; h++) s += tile[h][w];
    (ten ? cs_fy : cs_fx)[bc * 80 + w] = s;
  }
}

// ---- K5: combine over ci -> inverse norms.
// invn: [0]=H_fy(q) [Nb*640]=H_fx(k) [2*Nb*640]=W_fx(q) [3*Nb*640]=W_fy(k) ----
__global__ __launch_bounds__(256) void norm_combine(const float* __restrict__ rs_fx,
    const float* __restrict__ rs_fy, const float* __restrict__ cs_fx,
    const float* __restrict__ cs_fy, float* __restrict__ invn, int Nb)
{
  int t = blockIdx.x * 256 + threadIdx.x;   // 4*Nb*640 total
  int blk = Nb * 640;
  int side = t / blk, r = t % blk;
  int b = r / 640, rem = r % 640, hd = rem / 80, row = rem % 80;
  const float* src = (side == 0) ? rs_fy : (side == 1) ? rs_fx : (side == 2) ? cs_fx : cs_fy;
  size_t base = (size_t)(b * 256 + hd * 32) * 80 + row;
  float s = 0.f;
  #pragma unroll
  for (int ci = 0; ci < 32; ci++) s += src[base + ci * 80];
  invn[t] = 1.f / fmaxf(sqrtf(s), 1e-12f);
}

// ---- K6: Gram (sum over 32 ci) + cosine scale + softmax -> Sbuf ----
__global__ __launch_bounds__(256) void gram_softmax(const u16* __restrict__ fx, const u16* __restrict__ fy,
    const float* __restrict__ invn, u16* __restrict__ Sbuf, int Nb)
{
  __shared__ float At[80][81];
  __shared__ float Bt[80][81];
  int hd = blockIdx.x, b = blockIdx.y, axis = blockIdx.z;
  const u16* A  = axis ? fx : fy;   // q-side
  const u16* Bm = axis ? fy : fx;   // k-side
  size_t sl0 = (size_t)(b * 256 + hd * 32) * NHW;
  int t = threadIdx.x, tx = t & 15, ty = t >> 4;
  float acc[5][5] = {};
  for (int ci = 0; ci < 32; ci++) {
    const u16* pa = A  + sl0 + (size_t)ci * NHW;
    const u16* pb = Bm + sl0 + (size_t)ci * NHW;
    for (int i = t; i < NHW; i += 256) {
      int h = i / 80, w = i % 80;
      float va = b2f(pa[i]), vb = b2f(pb[i]);
      if (axis == 0) { At[h][w] = va; Bt[h][w] = vb; }
      else           { At[w][h] = va; Bt[w][h] = vb; }
    }
    __syncthreads();
    for (int k = 0; k < 80; k++) {
      float a[5], bb[5];
      #pragma unroll
      for (int r = 0; r < 5; r++) a[r] = At[ty + 16 * r][k];
      #pragma unroll
      for (int s = 0; s < 5; s++) bb[s] = Bt[tx + 16 * s][k];
      #pragma unroll
      for (int r = 0; r < 5; r++)
        #pragma unroll
        for (int s = 0; s < 5; s++)
          acc[r][s] += a[r] * bb[s];
    }
    __syncthreads();
  }
  int blk = Nb * 640;
  int rowbase = (b * 8 + hd) * 80;
  const float* invq = invn + (axis ? 2 * blk : 0)   + rowbase;
  const float* invk = invn + (axis ? 3 * blk : blk) + rowbase;
  #pragma unroll
  for (int r = 0; r < 5; r++)
    #pragma unroll
    for (int s = 0; s < 5; s++) {
      float gv = acc[r][s] * invq[ty + 16 * r] * invk[tx + 16 * s];
      At[ty + 16 * r][tx + 16 * s] = fminf(fmaxf(gv, -8.f), 8.f);  // |cos|<=1; NaN->-8
    }
  __syncthreads();
  u16* Sg = Sbuf + ((size_t)(axis * Nb * 8 + b * 8 + hd)) * NHW;
  if (t < 80) {
    float m = -1e30f;
    for (int j = 0; j < 80; j++) m = fmaxf(m, At[t][j]);
    float s = 0.f;
    for (int j = 0; j < 80; j++) s += __expf(At[t][j] - m);
    float inv = 1.f / s;
    for (int j = 0; j < 80; j++) Sg[t * 80 + j] = f2b(__expf(At[t][j] - m) * inv);
  }
}

// ---- K7: fused H+W attention apply, IN PLACE over fx slice ----
__global__ __launch_bounds__(256) void apply_hw(const u16* __restrict__ fy_g,
    const u16* __restrict__ Sbuf, const float* __restrict__ invn, u16* fx_io, int Nb)
{
  __shared__ float SH[80][81];
  __shared__ float SW[80][81];
  __shared__ float FX[80][81];
  __shared__ float FY[80][81];
  int ci = blockIdx.x, hd = blockIdx.y, b = blockIdx.z;
  size_t off = (size_t)(b * 256 + hd * 32 + ci) * NHW;
  const u16* SgH = Sbuf + (size_t)(b * 8 + hd) * NHW;
  const u16* SgW = Sbuf + ((size_t)(Nb * 8) + b * 8 + hd) * NHW;
  int t = threadIdx.x, tx = t & 15, ty = t >> 4;
  for (int i = t; i < NHW; i += 256) {
    int h = i / 80, w = i % 80;
    SH[h][w] = b2f(SgH[i]);
    SW[h][w] = b2f(SgW[i]);
    FX[h][w] = b2f(fx_io[off + i]);
    FY[h][w] = b2f(fy_g[off + i]);
  }
  __syncthreads();
  float accH[5][5] = {}, accW[5][5] = {};
  for (int k = 0; k < 80; k++) {
    float a[5], bv[5], c[5], d[5];
    #pragma unroll
    for (int r = 0; r < 5; r++) a[r] = SH[ty + 16 * r][k];   // S_H[h][k]
    #pragma unroll
    for (int s = 0; s < 5; s++) bv[s] = FX[k][tx + 16 * s];  // fx[k][w]
    #pragma unroll
    for (int r = 0; r < 5; r++) c[r] = FY[ty + 16 * r][k];   // fy[h][k]
    #pragma unroll
    for (int s = 0; s < 5; s++) d[s] = SW[tx + 16 * s][k];   // S_W[w][k]
    #pragma unroll
    for (int r = 0; r < 5; r++)
      #pragma unroll
      for (int s = 0; s < 5; s++) {
        accH[r][s] += a[r] * bv[s];
        accW[r][s] += c[r] * d[s];
      }
  }
  const float* invqH = invn + (b * 8 + hd) * 80;                 // H_fy(q)
  const float* invqW = invn + 2 * Nb * 640 + (b * 8 + hd) * 80;  // W_fx(q)
  #pragma unroll
  for (int r = 0; r < 5; r++)
    #pragma unroll
    for (int s = 0; s < 5; s++) {
      int h = ty + 16 * r, w = tx + 16 * s;
      float v = accH[r][s] + accW[r][s] + FY[h][w] * invqH[h] + FX[h][w] * invqW[w];
      fx_io[off + h * 80 + w] = f2b(v);
    }
}

extern "C" void kernel_launch(void* const* d_in, const int* in_sizes, int n_in,
                              void* d_out, int out_size, void* d_ws, size_t ws_size,
                              hipStream_t stream) {
  // Weight conversion table: d_in[1..18] in setup_inputs order.
  const int wsz[18] = {256, 256, 65536, 256, 65536, 256,
                       1792, 256, 2816, 256, 5376, 256,
                       1792, 256, 2816, 256, 5376, 256};
  CvtArgs ca;
  int cum = 0;
  for (int i = 0; i < 18; i++) { ca.src[i] = d_in[i + 1]; ca.cum[i] = cum; cum += wsz[i]; }
  ca.cum[18] = cum;   // 153600

  // ws layout: flag(16) | wbuf(614400) | per-chunk (Nb * 7,147,520).
  int Nb = 1;
  for (int cand = 16; cand >= 1; cand >>= 1) {
    size_t need = (size_t)cand * 7147520 + 614416;
    if (need <= ws_size) { Nb = cand; break; }
  }
  char* p = (char*)d_ws;
  int*    flag  = (int*)p;    p += 16;
  float*  wbuf  = (float*)p;  p += 614400;
  u16*    fxbuf = (u16*)p;    p += (size_t)Nb * 3276800;
  u16*    fybuf = (u16*)p;    p += (size_t)Nb * 3276800;
  float2* stats = (float2*)p; p += (size_t)Nb * 51200;
  float*  rs_fx = (float*)p;  p += (size_t)Nb * 81920;
  float*  rs_fy = (float*)p;  p += (size_t)Nb * 81920;
  float*  cs_fx = (float*)p;  p += (size_t)Nb * 81920;
  float*  cs_fy = (float*)p;  p += (size_t)Nb * 81920;
  float*  invn  = (float*)p;  p += (size_t)Nb * 10240;
  u16*    Sbuf  = (u16*)p;

  // f32 weight views
  float* ln_g = wbuf + ca.cum[0];  float* ln_b = wbuf + ca.cum[1];
  float* w_in = wbuf + ca.cum[2];  float* b_in = wbuf + ca.cum[3];
  float* w_out= wbuf + ca.cum[4];  float* b_out= wbuf + ca.cum[5];
  float* wx7  = wbuf + ca.cum[6];  float* bx7  = wbuf + ca.cum[7];
  float* wx11 = wbuf + ca.cum[8];  float* bx11 = wbuf + ca.cum[9];
  float* wx21 = wbuf + ca.cum[10]; float* bx21 = wbuf + ca.cum[11];
  float* wy7  = wbuf + ca.cum[12]; float* by7  = wbuf + ca.cum[13];
  float* wy11 = wbuf + ca.cum[14]; float* by11 = wbuf + ca.cum[15];
  float* wy21 = wbuf + ca.cum[16]; float* by21 = wbuf + ca.cum[17];

  probe_dtype<<<dim3(1), dim3(256), 0, stream>>>((const u16*)d_in[0], flag);
  cvt_weights<<<dim3(600), dim3(256), 0, stream>>>(ca, wbuf, flag);

  for (int b0 = 0; b0 < NB; b0 += Nb) {
    size_t xoff = (size_t)b0 * NC * NHW;   // element offset of chunk in x / out

    ln_stats<<<dim3(Nb * 25), dim3(256), 0, stream>>>(d_in[0], xoff, flag, stats);
    dw_both<<<dim3(Nb * 256), dim3(256), 0, stream>>>(d_in[0], xoff, flag, stats,
        ln_g, ln_b, wx7, bx7, wx11, bx11, wx21, bx21,
        wy7, by7, wy11, by11, wy21, by21, fxbuf, fybuf);
    pw_inplace<<<dim3(100, Nb), dim3(256), 0, stream>>>(w_in, fxbuf, b_in);
    pw_inplace<<<dim3(100, Nb), dim3(256), 0, stream>>>(w_in, fybuf, b_in);
    rowcol_sumsq<<<dim3(Nb * 256, 2), dim3(256), 0, stream>>>(fxbuf, fybuf, rs_fx, rs_fy, cs_fx, cs_fy);
    norm_combine<<<dim3(10 * Nb), dim3(256), 0, stream>>>(rs_fx, rs_fy, cs_fx, cs_fy, invn, Nb);
    gram_softmax<<<dim3(8, Nb, 2), dim3(256), 0, stream>>>(fxbuf, fybuf, invn, Sbuf, Nb);
    apply_hw<<<dim3(32, 8, Nb), dim3(256), 0, stream>>>(fybuf, Sbuf, invn, fxbuf, Nb);
    pw_final<<<dim3(100, Nb), dim3(256), 0, stream>>>(w_out, fxbuf, d_out, xoff, b_out,
                                                      d_in[0], xoff, flag);
  }
  (void)in_sizes; (void)n_in; (void)out_size;
}